// Round 1
// 620.176 us; speedup vs baseline: 1.1225x; 1.1225x over previous
//
#include <hip/hip_runtime.h>
#include <cstdint>
#include <cstddef>

// Problem constants
#define MROWS 8192   // B*C = 32*256
#define VIN   6890   // K (real)
#define VOUT  1723   // N (real)
#define KP    6912   // K padded: 108 * 64
#define NP    1792   // N padded: 7 * 256
#define TK    108    // K tiles of 64

typedef __attribute__((ext_vector_type(8))) __bf16 bf16x8;  // 4 VGPRs, A/B frag
typedef __attribute__((ext_vector_type(4))) float f32x4;    // C/D frag

// ---------------- fp32 -> bf16 (RNE) ----------------
__device__ __forceinline__ uint32_t f2bf(float f) {
    uint32_t u = __builtin_bit_cast(uint32_t, f);
    u += 0x7fffu + ((u >> 16) & 1u);
    return u >> 16;
}

// x: [MROWS][VIN] fp32 -> xb: [MROWS][KP] bf16 (zero-padded K tail)
__global__ __launch_bounds__(256) void cvt_x_kernel(
        const float* __restrict__ x, uint16_t* __restrict__ xb) {
    const int row = blockIdx.y;
    const int g   = blockIdx.x * blockDim.x + threadIdx.x;  // 8-float group
    if (g >= KP / 8) return;
    const int c = g * 8;
    uint32_t w[4];
#pragma unroll
    for (int p = 0; p < 4; ++p) {
        const int cc = c + p * 2;
        float2 f = make_float2(0.f, 0.f);
        if (cc < VIN)  // VIN even -> pair fully valid or fully pad
            f = *(const float2*)(x + (size_t)row * VIN + cc);
        w[p] = f2bf(f.x) | (f2bf(f.y) << 16);
    }
    uint4 o; o.x = w[0]; o.y = w[1]; o.z = w[2]; o.w = w[3];
    *(uint4*)(xb + (size_t)row * KP + c) = o;
}

// M: [VOUT][VIN] fp32 -> mb: [NP][KP] bf16 (zero-padded rows & K tail)
__global__ __launch_bounds__(256) void cvt_m_kernel(
        const float* __restrict__ m, uint16_t* __restrict__ mb) {
    const int row = blockIdx.y;
    const int g   = blockIdx.x * blockDim.x + threadIdx.x;
    if (g >= KP / 8) return;
    const int c = g * 8;
    uint32_t w[4];
    const bool rv = (row < VOUT);
#pragma unroll
    for (int p = 0; p < 4; ++p) {
        const int cc = c + p * 2;
        float2 f = make_float2(0.f, 0.f);
        if (rv && cc < VIN)
            f = *(const float2*)(m + (size_t)row * VIN + cc);
        w[p] = f2bf(f.x) | (f2bf(f.y) << 16);
    }
    uint4 o; o.x = w[0]; o.y = w[1]; o.z = w[2]; o.w = w[3];
    *(uint4*)(mb + (size_t)row * KP + c) = o;
}

// ---------------- async global -> LDS, 16B/lane ----------------
__device__ __forceinline__ void gload_lds16(const void* g, void* l) {
    __builtin_amdgcn_global_load_lds(
        (const __attribute__((address_space(1))) void*)g,
        (__attribute__((address_space(3))) void*)l,
        16, 0, 0);
}

#define BAR()   __builtin_amdgcn_s_barrier()
#define LGKM0() asm volatile("s_waitcnt lgkmcnt(0)" ::: "memory")

// ---------------- 256x256 8-phase bf16 MFMA GEMM ----------------
// C[m,n] = sum_k X[m,k] * W[n,k].  BM=BN=256, BK=64, 8 waves (2M x 4N),
// per-wave 128x64 output (acc[8][4] of 16x16 frags), 64 MFMA/K-tile/wave.
//
// LDS: per operand [buf2][half2][128 rows][64 cols] bf16, 64KB -> 128KB total.
// Staging: global_load_lds 16B/lane, LINEAR dest (wave w, issue q covers rows
// q*64+w*8..+8). Bank-conflict swizzle: LDS granule s at row r holds global
// granule s ^ (r&7); applied by pre-swizzling the per-lane GLOBAL source
// (gsrc = (l&7)^(l>>3)) and XOR-ing the ds_read address identically.
//
// Half-tile schedule (derived; stage stream 3 half-tiles ahead, vmcnt(6)
// retires exactly through tile t+1 once per tile):
//   phase0: ds_read all A + B c0-1; stage (t+1):B1; mfma r0-3 x c0-1
//   phase1: ds_read B c2-3;         stage (t+2):A0; mfma r4-7 x c0-1
//   phase2:                         stage (t+2):A1; mfma r0-3 x c2-3
//   phase3:                         stage (t+2):B0; mfma r4-7 x c2-3; vmcnt(6)
// Overwrite safety: A-halves fully reg-loaded in phase0 (barrier before the
// (t+2):A stages); B reads finish by phase1 (barrier before (t+2):B0 at ph3).
__global__ __launch_bounds__(512, 2) void gemm_bt_kernel(
        const uint16_t* __restrict__ X,    // [MROWS][KP] bf16 bits
        const uint16_t* __restrict__ W,    // [NP][KP]   bf16 bits
        float* __restrict__ out) {         // [MROWS][VOUT] fp32
    __shared__ uint16_t lsA[2 * 2 * 8192];  // 64 KB
    __shared__ uint16_t lsB[2 * 2 * 8192];  // 64 KB

    const int tid  = threadIdx.x;
    const int wave = tid >> 6;
    const int lane = tid & 63;
    const int wm   = wave >> 2;   // 0..1 (row half)
    const int wn   = wave & 3;    // 0..3 (64-col slice)
    const int bm   = blockIdx.y;  // 0..31
    const int bn   = blockIdx.x;  // 0..6

    const int l15  = lane & 15;
    const int l7   = lane & 7;
    const int gq   = lane >> 4;                 // 0..3
    const int tr8  = tid >> 3;                  // 0..63 = wave*8 + (lane>>3)
    const int gsrc = (lane & 7) ^ (lane >> 3);  // pre-swizzled source granule

    // per-lane global staging bases
    const uint16_t* gA = X + (size_t)(bm * 256 + tr8) * KP + gsrc * 8;
    const uint16_t* gB = W + (size_t)(bn * 256 + tr8) * KP + gsrc * 8;

    // stage one half-tile (2 x global_load_lds per wave), guarded on u < TK
#define STG(u, h, gptr, larr) do { if ((u) < TK) {                                   \
        uint16_t* _d = &larr[(((u) & 1) * 2 + (h)) * 8192 + wave * 512];             \
        const uint16_t* _s = gptr + (size_t)((h) * 128) * KP + (size_t)(u) * 64;     \
        gload_lds16(_s, _d);                                                         \
        gload_lds16(_s + (size_t)64 * KP, _d + 4096);                                \
    } } while (0)

    f32x4 acc[8][4] = {};

    // prologue: tile0 {A0,A1,B0,B1} + tile1 {A0,A1,B0} = 14 loads/wave; keep 6
    STG(0, 0, gA, lsA); STG(0, 1, gA, lsA); STG(0, 0, gB, lsB); STG(0, 1, gB, lsB);
    STG(1, 0, gA, lsA); STG(1, 1, gA, lsA); STG(1, 0, gB, lsB);
    asm volatile("s_waitcnt vmcnt(6)" ::: "memory");
    BAR();

#define ARD(i, kk) af[i][kk] = *(const bf16x8*)(hA + ((i) * 16 + l15) * 64 + ((((kk) * 4 + gq) ^ l7) * 8))
#define BRD(j, kk) bfr[j][kk] = *(const bf16x8*)(hB + ((wn & 1) * 64 + (j) * 16 + l15) * 64 + ((((kk) * 4 + gq) ^ l7) * 8))
#define QUAD(IB, JB) do {                                                            \
        __builtin_amdgcn_s_setprio(1);                                               \
        _Pragma("unroll")                                                            \
        for (int kk = 0; kk < 2; ++kk)                                               \
            _Pragma("unroll")                                                        \
            for (int i = 0; i < 4; ++i)                                              \
                _Pragma("unroll")                                                    \
                for (int j = 0; j < 2; ++j)                                          \
                    acc[(IB) + i][(JB) + j] = __builtin_amdgcn_mfma_f32_16x16x32_bf16( \
                        af[(IB) + i][kk], bfr[(JB) + j][kk], acc[(IB) + i][(JB) + j], 0, 0, 0); \
        __builtin_amdgcn_s_setprio(0);                                               \
    } while (0)

    for (int t = 0; t < TK; ++t) {
        const uint16_t* hA = &lsA[((t & 1) * 2 + wm) * 8192];
        const uint16_t* hB = &lsB[((t & 1) * 2 + (wn >> 1)) * 8192];
        bf16x8 af[8][2];   // wave's full A-half: 64 VGPR
        bf16x8 bfr[4][2];  // wave's B slice:     32 VGPR

        // ---- phase 0: all A frags + B cols 0-1; stage (t+1):B1
        ARD(0, 0); ARD(0, 1); ARD(1, 0); ARD(1, 1);
        ARD(2, 0); ARD(2, 1); ARD(3, 0); ARD(3, 1);
        ARD(4, 0); ARD(4, 1); ARD(5, 0); ARD(5, 1);
        ARD(6, 0); ARD(6, 1); ARD(7, 0); ARD(7, 1);
        BRD(0, 0); BRD(0, 1); BRD(1, 0); BRD(1, 1);
        STG(t + 1, 1, gB, lsB);
        BAR(); LGKM0();
        QUAD(0, 0);
        BAR();

        // ---- phase 1: B cols 2-3; stage (t+2):A0
        BRD(2, 0); BRD(2, 1); BRD(3, 0); BRD(3, 1);
        STG(t + 2, 0, gA, lsA);
        BAR(); LGKM0();
        QUAD(4, 0);
        BAR();

        // ---- phase 2: stage (t+2):A1
        STG(t + 2, 1, gA, lsA);
        BAR(); LGKM0();
        QUAD(0, 2);
        BAR();

        // ---- phase 3: stage (t+2):B0; counted vmcnt (never 0 mid-loop)
        STG(t + 2, 0, gB, lsB);
        BAR(); LGKM0();
        QUAD(4, 2);
        if (t + 2 < TK) { asm volatile("s_waitcnt vmcnt(6)" ::: "memory"); }
        else            { asm volatile("s_waitcnt vmcnt(0)" ::: "memory"); }
        BAR();
    }
#undef ARD
#undef BRD
#undef QUAD
#undef STG

    // epilogue: C/D layout col = lane&15, row = (lane>>4)*4 + reg  [m89/m91]
    const int r0 = bm * 256 + wm * 128 + (lane >> 4) * 4;
    const int c0 = bn * 256 + wn * 64 + l15;
#pragma unroll
    for (int j = 0; j < 4; ++j) {
        const int col = c0 + j * 16;
        if (col < VOUT) {
#pragma unroll
            for (int i = 0; i < 8; ++i) {
                const int rr = r0 + i * 16;
#pragma unroll
                for (int r = 0; r < 4; ++r)
                    out[(size_t)(rr + r) * VOUT + col] = acc[i][j][r];
            }
        }
    }
}

// ---------------- fp32 fallback (only if ws too small) ----------------
__global__ void fallback_kernel(const float* __restrict__ x,
                                const float* __restrict__ M,
                                float* __restrict__ out) {
    const int m = blockIdx.y;
    const int o = blockIdx.x * blockDim.x + threadIdx.x;
    if (o >= VOUT) return;
    const float* xr = x + (size_t)m * VIN;
    const float* mr = M + (size_t)o * VIN;
    float s = 0.f;
    for (int k = 0; k < VIN; ++k) s = fmaf(xr[k], mr[k], s);
    out[(size_t)m * VOUT + o] = s;
}

extern "C" void kernel_launch(void* const* d_in, const int* in_sizes, int n_in,
                              void* d_out, int out_size, void* d_ws, size_t ws_size,
                              hipStream_t stream) {
    const float* x = (const float*)d_in[0];
    const float* M = (const float*)d_in[1];
    float* out = (float*)d_out;

    const size_t need = ((size_t)MROWS * KP + (size_t)NP * KP) * sizeof(uint16_t);
    if (ws_size < need) {
        fallback_kernel<<<dim3((VOUT + 255) / 256, MROWS), dim3(256), 0, stream>>>(x, M, out);
        return;
    }

    uint16_t* xb = (uint16_t*)d_ws;
    uint16_t* mb = xb + (size_t)MROWS * KP;

    const dim3 cblk(256);
    const int gx = (KP / 8 + 255) / 256;  // 4
    cvt_x_kernel<<<dim3(gx, MROWS), cblk, 0, stream>>>(x, xb);
    cvt_m_kernel<<<dim3(gx, NP),    cblk, 0, stream>>>(M, mb);

    gemm_bt_kernel<<<dim3(NP / 256, MROWS / 256), dim3(512), 0, stream>>>(xb, mb, out);
}

// Round 2
// 619.832 us; speedup vs baseline: 1.1231x; 1.0006x over previous
//
#include <hip/hip_runtime.h>
#include <cstdint>
#include <cstddef>

// Problem constants
#define MROWS 8192   // B*C = 32*256
#define VIN   6890   // K (real)
#define VOUT  1723   // N (real)
#define KP    6912   // K padded: 108 * 64
#define NP    1792   // N padded: 7 * 256
#define TK    108    // K tiles of 64

typedef __attribute__((ext_vector_type(8))) __bf16 bf16x8;  // 4 VGPRs, A/B frag
typedef __attribute__((ext_vector_type(4))) float f32x4;    // C/D frag

// ---------------- fp32 -> bf16 (RNE) ----------------
__device__ __forceinline__ uint32_t f2bf(float f) {
    uint32_t u = __builtin_bit_cast(uint32_t, f);
    u += 0x7fffu + ((u >> 16) & 1u);
    return u >> 16;
}

// x: [MROWS][VIN] fp32 -> xb: [MROWS][KP] bf16 (zero-padded K tail)
__global__ __launch_bounds__(256) void cvt_x_kernel(
        const float* __restrict__ x, uint16_t* __restrict__ xb) {
    const int row = blockIdx.y;
    const int g   = blockIdx.x * blockDim.x + threadIdx.x;  // 8-float group
    if (g >= KP / 8) return;
    const int c = g * 8;
    uint32_t w[4];
#pragma unroll
    for (int p = 0; p < 4; ++p) {
        const int cc = c + p * 2;
        float2 f = make_float2(0.f, 0.f);
        if (cc < VIN)  // VIN even -> pair fully valid or fully pad
            f = *(const float2*)(x + (size_t)row * VIN + cc);
        w[p] = f2bf(f.x) | (f2bf(f.y) << 16);
    }
    uint4 o; o.x = w[0]; o.y = w[1]; o.z = w[2]; o.w = w[3];
    *(uint4*)(xb + (size_t)row * KP + c) = o;
}

// M: [VOUT][VIN] fp32 -> mb: [NP][KP] bf16 (zero-padded rows & K tail)
__global__ __launch_bounds__(256) void cvt_m_kernel(
        const float* __restrict__ m, uint16_t* __restrict__ mb) {
    const int row = blockIdx.y;
    const int g   = blockIdx.x * blockDim.x + threadIdx.x;
    if (g >= KP / 8) return;
    const int c = g * 8;
    uint32_t w[4];
    const bool rv = (row < VOUT);
#pragma unroll
    for (int p = 0; p < 4; ++p) {
        const int cc = c + p * 2;
        float2 f = make_float2(0.f, 0.f);
        if (rv && cc < VIN)
            f = *(const float2*)(m + (size_t)row * VIN + cc);
        w[p] = f2bf(f.x) | (f2bf(f.y) << 16);
    }
    uint4 o; o.x = w[0]; o.y = w[1]; o.z = w[2]; o.w = w[3];
    *(uint4*)(mb + (size_t)row * KP + c) = o;
}

// ---------------- async global -> LDS, 16B/lane ----------------
__device__ __forceinline__ void gload_lds16(const void* g, void* l) {
    __builtin_amdgcn_global_load_lds(
        (const __attribute__((address_space(1))) void*)g,
        (__attribute__((address_space(3))) void*)l,
        16, 0, 0);
}

#define BAR()   __builtin_amdgcn_s_barrier()
#define LGKM0() asm volatile("s_waitcnt lgkmcnt(0)" ::: "memory")

// ---------------- 256x256 4-phase bf16 MFMA GEMM, A triple-buffered ----------------
// C[m,n] = sum_k X[m,k] * W[n,k].  BM=BN=256, BK=64, 8 waves (2M x 4N),
// per-wave 128x64 output (acc[8][4] of 16x16 frags), 64 MFMA/K-tile/wave.
//
// LDS: A = 3 bufs x [2 halves][128][64] bf16 = 96 KB (parity t%3),
//      B = 2 bufs x [2 halves][128][64] bf16 = 64 KB (parity t&1). 160 KB total.
//
// Why triple-buffer A: it decouples A-fragment reads from A staging, so the
// 24 ds_read_b128/wave/tile spread {8,8,4,4} across the 4 phases instead of
// bunching 20 in phase 0 (R1's measured LDS/MFMA serialization). Per phase
// LDS <= 768 cy/CU vs 620 cy MFMA -> near-full overlap via the barrier +
// own-lgkmcnt(0) wave stagger (m201 mechanism).
//
// Per tile t (alo = A rows 0-63 of wave's half, PRE-READ during tile t-1):
//   ph0: read ahi[0-1],bfr[0-1] (8); stage A0(t+2); BAR; lgkm0; Q(r0-3 x c0-1)
//   ph1: read ahi[2-3],bfr[2-3] (8); stage A1(t+2); BAR; lgkm0; Q(r0-3 x c2-3)
//   ph2: read alo(t+1)[0-1]     (4);               BAR; lgkm0; Q(r4-7 x c0-1)
//   ph3: read alo(t+1)[2-3]     (4); stage B0+B1(t+2); BAR; lgkm0; Q(r4-7 x c2-3);
//        vmcnt(4) [tail: vmcnt(0)]; BAR
//
// Hazards (all read-retire -> barrier -> overwrite-issue ordered):
//  - bfr(t) reads retire by ph1 lgkm0; B(t+2) staged ph3.           OK
//  - ahi(t) reads retire by ph1 lgkm0; buffer t%3 overwritten by
//    A(t+3) staged at tile t+1 ph0.                                 OK
//  - alo(t+1) reads (tile t ph2-3) from buffer (t+1)%3; overwritten
//    by A(t+4) staged tile t+2 ph0.                                 OK
// vmcnt(4) at tile-t end: outstanding (oldest first) = B(t+1)[4],
// A0(t+2)[2], A1(t+2)[2], B(t+2)[4] -> retires B(t+1)+A(t+2), exactly
// what tile t+1 reads (ahi/bfr at ph0, alo(t+2) at ph2).
__global__ __launch_bounds__(512, 2) void gemm_bt_kernel(
        const uint16_t* __restrict__ X,    // [MROWS][KP] bf16 bits
        const uint16_t* __restrict__ W,    // [NP][KP]   bf16 bits
        float* __restrict__ out) {         // [MROWS][VOUT] fp32
    __shared__ uint16_t lsA[3 * 2 * 8192];  // 96 KB
    __shared__ uint16_t lsB[2 * 2 * 8192];  // 64 KB

    const int tid  = threadIdx.x;
    const int wave = tid >> 6;
    const int lane = tid & 63;
    const int wm   = wave >> 2;   // 0..1 (row half)
    const int wn   = wave & 3;    // 0..3 (64-col slice)
    const int bm   = blockIdx.y;  // 0..31
    const int bn   = blockIdx.x;  // 0..6

    const int l15  = lane & 15;
    const int l7   = lane & 7;
    const int gq   = lane >> 4;                 // 0..3
    const int tr8  = tid >> 3;                  // 0..63 = wave*8 + (lane>>3)
    const int gsrc = (lane & 7) ^ (lane >> 3);  // pre-swizzled source granule

    // per-lane global staging bases
    const uint16_t* gA = X + (size_t)(bm * 256 + tr8) * KP + gsrc * 8;
    const uint16_t* gB = W + (size_t)(bn * 256 + tr8) * KP + gsrc * 8;

    // stage one half-tile (2 x global_load_lds per wave); pb = LDS buffer idx
#define STG_A(u, h, pb) do { if ((u) < TK) {                                         \
        uint16_t* _d = &lsA[(pb) * 16384 + (h) * 8192 + wave * 512];                 \
        const uint16_t* _s = gA + (size_t)((h) * 128) * KP + (size_t)(u) * 64;       \
        gload_lds16(_s, _d);                                                         \
        gload_lds16(_s + (size_t)64 * KP, _d + 4096);                                \
    } } while (0)
#define STG_B(u, h) do { if ((u) < TK) {                                             \
        uint16_t* _d = &lsB[(((u) & 1) * 2 + (h)) * 8192 + wave * 512];              \
        const uint16_t* _s = gB + (size_t)((h) * 128) * KP + (size_t)(u) * 64;       \
        gload_lds16(_s, _d);                                                         \
        gload_lds16(_s + (size_t)64 * KP, _d + 4096);                                \
    } } while (0)

    // swizzled ds_reads (same XOR involution as the staging source)
#define ALO_RD(P, i, kk) alo[i][kk] = *(const bf16x8*)((P) + ((i) * 16 + l15) * 64 + ((((kk) * 4 + gq) ^ l7) * 8))
#define AHI_RD(P, i, kk) ahi[i][kk] = *(const bf16x8*)((P) + (((i) + 4) * 16 + l15) * 64 + ((((kk) * 4 + gq) ^ l7) * 8))
#define B_RD(P, j, kk)   bfr[j][kk] = *(const bf16x8*)((P) + ((wn & 1) * 64 + (j) * 16 + l15) * 64 + ((((kk) * 4 + gq) ^ l7) * 8))

#define QUAD_LO(JB) do {                                                             \
        __builtin_amdgcn_s_setprio(1);                                               \
        _Pragma("unroll")                                                            \
        for (int kk = 0; kk < 2; ++kk)                                               \
            _Pragma("unroll")                                                        \
            for (int i = 0; i < 4; ++i)                                              \
                _Pragma("unroll")                                                    \
                for (int j = 0; j < 2; ++j)                                          \
                    acc[i][(JB) + j] = __builtin_amdgcn_mfma_f32_16x16x32_bf16(      \
                        alo[i][kk], bfr[(JB) + j][kk], acc[i][(JB) + j], 0, 0, 0);   \
        __builtin_amdgcn_s_setprio(0);                                               \
    } while (0)
#define QUAD_HI(JB) do {                                                             \
        __builtin_amdgcn_s_setprio(1);                                               \
        _Pragma("unroll")                                                            \
        for (int kk = 0; kk < 2; ++kk)                                               \
            _Pragma("unroll")                                                        \
            for (int i = 0; i < 4; ++i)                                              \
                _Pragma("unroll")                                                    \
                for (int j = 0; j < 2; ++j)                                          \
                    acc[4 + i][(JB) + j] = __builtin_amdgcn_mfma_f32_16x16x32_bf16(  \
                        ahi[i][kk], bfr[(JB) + j][kk], acc[4 + i][(JB) + j], 0, 0, 0); \
        __builtin_amdgcn_s_setprio(0);                                               \
    } while (0)

    f32x4 acc[8][4] = {};
    bf16x8 alo[4][2], ahi[4][2], bfr[4][2];

    // prologue: stage A(0),B(0),A(1),B(1) = 16 loads; retire A(0),B(0)
    STG_A(0, 0, 0); STG_A(0, 1, 0); STG_B(0, 0); STG_B(0, 1);
    STG_A(1, 0, 1); STG_A(1, 1, 1); STG_B(1, 0); STG_B(1, 1);
    asm volatile("s_waitcnt vmcnt(8)" ::: "memory");
    BAR();

    // pre-read alo(0) (waited by tile 0 ph0's lgkm0)
    {
        const uint16_t* hA0 = &lsA[wm * 8192];
        ALO_RD(hA0, 0, 0); ALO_RD(hA0, 0, 1); ALO_RD(hA0, 1, 0); ALO_RD(hA0, 1, 1);
        ALO_RD(hA0, 2, 0); ALO_RD(hA0, 2, 1); ALO_RD(hA0, 3, 0); ALO_RD(hA0, 3, 1);
    }

    int pc = 0;  // t % 3
    for (int t = 0; t < TK; ++t) {
        const int pn = (pc == 2) ? 0 : pc + 1;        // (t+1) % 3
        const int ps = (pn == 2) ? 0 : pn + 1;        // (t+2) % 3
        const uint16_t* hA  = &lsA[pc * 16384 + wm * 8192];
        const uint16_t* hAn = &lsA[pn * 16384 + wm * 8192];
        const uint16_t* hB  = &lsB[(t & 1) * 16384 + (wn >> 1) * 8192];

        // ---- phase 0
        AHI_RD(hA, 0, 0); AHI_RD(hA, 0, 1); AHI_RD(hA, 1, 0); AHI_RD(hA, 1, 1);
        B_RD(hB, 0, 0); B_RD(hB, 0, 1); B_RD(hB, 1, 0); B_RD(hB, 1, 1);
        STG_A(t + 2, 0, ps);
        BAR(); LGKM0();
        QUAD_LO(0);
        BAR();

        // ---- phase 1
        AHI_RD(hA, 2, 0); AHI_RD(hA, 2, 1); AHI_RD(hA, 3, 0); AHI_RD(hA, 3, 1);
        B_RD(hB, 2, 0); B_RD(hB, 2, 1); B_RD(hB, 3, 0); B_RD(hB, 3, 1);
        STG_A(t + 2, 1, ps);
        BAR(); LGKM0();
        QUAD_LO(2);
        BAR();

        // ---- phase 2
        ALO_RD(hAn, 0, 0); ALO_RD(hAn, 0, 1); ALO_RD(hAn, 1, 0); ALO_RD(hAn, 1, 1);
        BAR(); LGKM0();
        QUAD_HI(0);
        BAR();

        // ---- phase 3
        ALO_RD(hAn, 2, 0); ALO_RD(hAn, 2, 1); ALO_RD(hAn, 3, 0); ALO_RD(hAn, 3, 1);
        STG_B(t + 2, 0); STG_B(t + 2, 1);
        BAR(); LGKM0();
        QUAD_HI(2);
        if (t + 2 < TK) { asm volatile("s_waitcnt vmcnt(4)" ::: "memory"); }
        else            { asm volatile("s_waitcnt vmcnt(0)" ::: "memory"); }
        BAR();

        pc = pn;
    }
#undef ALO_RD
#undef AHI_RD
#undef B_RD
#undef QUAD_LO
#undef QUAD_HI
#undef STG_A
#undef STG_B

    // epilogue: C/D layout col = lane&15, row = (lane>>4)*4 + reg  [m89/m91]
    const int r0 = bm * 256 + wm * 128 + (lane >> 4) * 4;
    const int c0 = bn * 256 + wn * 64 + l15;
#pragma unroll
    for (int j = 0; j < 4; ++j) {
        const int col = c0 + j * 16;
        if (col < VOUT) {
#pragma unroll
            for (int i = 0; i < 8; ++i) {
                const int rr = r0 + i * 16;
#pragma unroll
                for (int r = 0; r < 4; ++r)
                    out[(size_t)(rr + r) * VOUT + col] = acc[i][j][r];
            }
        }
    }
}

// ---------------- fp32 fallback (only if ws too small) ----------------
__global__ void fallback_kernel(const float* __restrict__ x,
                                const float* __restrict__ M,
                                float* __restrict__ out) {
    const int m = blockIdx.y;
    const int o = blockIdx.x * blockDim.x + threadIdx.x;
    if (o >= VOUT) return;
    const float* xr = x + (size_t)m * VIN;
    const float* mr = M + (size_t)o * VIN;
    float s = 0.f;
    for (int k = 0; k < VIN; ++k) s = fmaf(xr[k], mr[k], s);
    out[(size_t)m * VOUT + o] = s;
}

extern "C" void kernel_launch(void* const* d_in, const int* in_sizes, int n_in,
                              void* d_out, int out_size, void* d_ws, size_t ws_size,
                              hipStream_t stream) {
    const float* x = (const float*)d_in[0];
    const float* M = (const float*)d_in[1];
    float* out = (float*)d_out;

    const size_t need = ((size_t)MROWS * KP + (size_t)NP * KP) * sizeof(uint16_t);
    if (ws_size < need) {
        fallback_kernel<<<dim3((VOUT + 255) / 256, MROWS), dim3(256), 0, stream>>>(x, M, out);
        return;
    }

    uint16_t* xb = (uint16_t*)d_ws;
    uint16_t* mb = xb + (size_t)MROWS * KP;

    const dim3 cblk(256);
    const int gx = (KP / 8 + 255) / 256;  // 4
    cvt_x_kernel<<<dim3(gx, MROWS), cblk, 0, stream>>>(x, xb);
    cvt_m_kernel<<<dim3(gx, NP),    cblk, 0, stream>>>(M, mb);

    gemm_bt_kernel<<<dim3(NP / 256, MROWS / 256), dim3(512), 0, stream>>>(xb, mb, out);
}